// Round 14
// baseline (256.335 us; speedup 1.0000x reference)
//
#include <hip/hip_runtime.h>
#include <hip/hip_bf16.h>

#define KC   1024
#define DD   256
#define NN   32768
#define HWC  1024
#define LOSS_OFF 8388608
#define IDX_OFF  8388609
#define CBT_OFF  2000000   // cbT[256][1024] in out's x_q region; gather overwrites later

// Replicate numpy pairwise_sum of a[i]*a[i], n=256 (validated: absmax 0.0 r2..r13).
__device__ __forceinline__ float np_pairwise_sumsq_256(const float* __restrict__ a) {
#pragma clang fp contract(off)
  float half0, half1;
  {
    const float* p = a;
    float r[8];
#pragma unroll
    for (int j = 0; j < 8; ++j) r[j] = p[j] * p[j];
    for (int i = 8; i < 128; i += 8) {
#pragma unroll
      for (int j = 0; j < 8; ++j) r[j] = r[j] + p[i + j] * p[i + j];
    }
    half0 = ((r[0] + r[1]) + (r[2] + r[3])) + ((r[4] + r[5]) + (r[6] + r[7]));
  }
  {
    const float* p = a + 128;
    float r[8];
#pragma unroll
    for (int j = 0; j < 8; ++j) r[j] = p[j] * p[j];
    for (int i = 8; i < 128; i += 8) {
#pragma unroll
      for (int j = 0; j < 8; ++j) r[j] = r[j] + p[i + j] * p[i + j];
    }
    half1 = ((r[0] + r[1]) + (r[2] + r[3])) + ((r[4] + r[5]) + (r[6] + r[7]));
  }
  return half0 + half1;
}

// K0: e_sq[k] via numpy-pairwise; zero loss accumulator.
__global__ void vq_esq_kernel(const float* __restrict__ cb, float* __restrict__ esq,
                              float* __restrict__ loss_acc) {
  const int k = blockIdx.x * 256 + threadIdx.x;
  if (k == 0) loss_acc[0] = 0.0f;
  if (k < KC) esq[k] = np_pairwise_sumsq_256(cb + ((size_t)k << 8));
}

// K0b: cbT[d][k] = cb[k][d] (1MB, L2-resident; makes argmin e-loads coalesced).
__global__ __launch_bounds__(256) void vq_transpose_kernel(const float* __restrict__ cb,
                                                           float* __restrict__ cbT) {
  const int d = blockIdx.x;     // 0..255
  const int t = threadIdx.x;
#pragma unroll
  for (int q = 0; q < 4; ++q) {
    const int k = (q << 8) + t;
    cbT[(d << 10) + k] = cb[((size_t)k << 8) + d];
  }
}

// K1: fused distance + argmin.
// CHANGE vs r13: work split re-cut to kill the duplicated e-stream.
//   wave w (0..3): code QUARTER [w*256, (w+1)*256) — the 4 waves' e-reads are
//   now DISJOINT: 1MB/block (was 2MB: rh-pairs re-read the same half) -> L1-
//   return 262Kcyc -> 131Kcyc in the serialized pipe sum (r13: 576K ~ 262 FMA
//   + 262 L1).
//   thread: 4 contiguous codes c0 = w*256 + lane*4, ALL 16 rows; acc[4][16]=64.
//   x via wave-uniform s_load (16 contiguous rows = s_load_dwordx16 per dim),
//   2-dim sub-chunks, double-buffered (2x32 SGPR, same budget as r13).
// Per-acc dim order ascending (sub-chunks ascending, d then d+1) — identical
// fl chain order; j ascending + explicit lowest-k shfl tie-break + ascending-w
// merge: tie machinery semantics unchanged (validated r2..r13).
__global__ __launch_bounds__(256, 2)
void vq_argmin_kernel(const float* __restrict__ x, const float* __restrict__ cbT,
                      const float* __restrict__ esq, int* __restrict__ idxout,
                      float* __restrict__ out) {
  __shared__ float xs[16][260];    // only for the xsq pairwise computation
  __shared__ float xsq[16];
  __shared__ float rbest[4][16];
  __shared__ int   rbidx[4][16];

  const int tid  = threadIdx.x;
  const int lane = tid & 63;
  const int w    = __builtin_amdgcn_readfirstlane(tid >> 6);  // 0..3, SGPR
  const int n0   = blockIdx.x << 4;   // 2048 blocks x 16 rows
  const int b    = n0 >> 10;
  const int hw0  = n0 & 1023;
  const float* __restrict__ xb = x + (size_t)b * (DD * HWC) + hw0;

  // Stage x tile for xsq: xs[r][d] = x[b, d, hw0+r].
  {
    const int rr = tid & 15;
    const int dq = tid >> 4;
#pragma unroll
    for (int i = 0; i < 16; ++i) {
      const int d = (i << 4) + dq;
      xs[rr][d] = xb[(size_t)d * HWC + rr];
    }
  }
  __syncthreads();

  // x_sq per row, numpy-pairwise bitwise (tie reproduction — do not change).
  if (tid < 16) xsq[tid] = np_pairwise_sumsq_256(&xs[tid][0]);
  __syncthreads();

  const int c0 = (w << 8) + (lane << 2);           // 4 contiguous codes
  float acc[4][16];                                // [code j][row r]
#pragma unroll
  for (int j = 0; j < 4; ++j)
#pragma unroll
    for (int r = 0; r < 16; ++r) acc[j][r] = 0.0f;

// Wave-uniform x for one 2-dim sub-chunk: XA[di][r] = x[b][2*SC+di][hw0+r],
// 16 contiguous floats per dim -> s_load_dwordx16 into SGPRs.
#define LOADX(XA, SC)                                                         \
  {                                                                           \
    _Pragma("unroll")                                                         \
    for (int di = 0; di < 2; ++di) {                                          \
      const float* __restrict__ rp_ = xb + (size_t)(((SC) << 1) + di) * HWC;  \
      _Pragma("unroll")                                                       \
      for (int r = 0; r < 16; ++r) XA[di][r] = rp_[r];                        \
    }                                                                         \
  }

// e for 4 contiguous codes at dims 2*SC, 2*SC+1: one float4 each, coalesced.
// Per-acc order: dim 2*SC then 2*SC+1 — ascending, matching the validated chain.
#define FMASUB(XA, SC)                                                        \
  {                                                                           \
    const float4 e0_ = *(const float4*)(cbT + ((size_t)((SC) << 1) << 10) + c0);       \
    const float4 e1_ = *(const float4*)(cbT + ((size_t)(((SC) << 1) + 1) << 10) + c0); \
    _Pragma("unroll")                                                         \
    for (int r = 0; r < 16; ++r) {                                            \
      acc[0][r] = fmaf(XA[0][r], e0_.x, acc[0][r]);                           \
      acc[0][r] = fmaf(XA[1][r], e1_.x, acc[0][r]);                           \
      acc[1][r] = fmaf(XA[0][r], e0_.y, acc[1][r]);                           \
      acc[1][r] = fmaf(XA[1][r], e1_.y, acc[1][r]);                           \
      acc[2][r] = fmaf(XA[0][r], e0_.z, acc[2][r]);                           \
      acc[2][r] = fmaf(XA[1][r], e1_.z, acc[2][r]);                           \
      acc[3][r] = fmaf(XA[0][r], e0_.w, acc[3][r]);                           \
      acc[3][r] = fmaf(XA[1][r], e1_.w, acc[3][r]);                           \
    }                                                                         \
  }

  float xa0[2][16], xa1[2][16];
  LOADX(xa0, 0)
  for (int sc = 0; sc < 128; sc += 2) {
    LOADX(xa1, sc + 1)                 // scalar prefetch hides K$/L2 latency
    FMASUB(xa0, sc)
    if (sc < 126) LOADX(xa0, sc + 2)
    FMASUB(xa1, sc + 1)
  }
#undef LOADX
#undef FMASUB

  // esq for 4 contiguous codes: one float4.
  const float4 eqv = *(const float4*)(esq + c0);
  const float eq[4] = {eqv.x, eqv.y, eqv.z, eqv.w};

#pragma unroll
  for (int r = 0; r < 16; ++r) {
    const float xq = xsq[r];
    float v; int ki;
    {
      // Reference rounding: fl(e_sq - fl(2*dot)) then fl(t + x_sq). No FMA here.
#pragma clang fp contract(off)
      v = (eq[0] - 2.0f * acc[0][r]) + xq; ki = c0;   // ascending j, strict <
#pragma unroll
      for (int j = 1; j < 4; ++j) {
        const float dj = (eq[j] - 2.0f * acc[j][r]) + xq;
        if (dj < v) { v = dj; ki = c0 + j; }
      }
    }
    // Wave-wide (val,idx) min, lowest k on ties.
#pragma unroll
    for (int off = 32; off >= 1; off >>= 1) {
      const float v2 = __shfl_xor(v, off, 64);
      const int   k2 = __shfl_xor(ki, off, 64);
      if (v2 < v || (v2 == v && k2 < ki)) { v = v2; ki = k2; }
    }
    if (lane == 0) { rbest[w][r] = v; rbidx[w][r] = ki; }
  }
  __syncthreads();

  // Merge the 4 code quarters per row in ascending w (= ascending k) order.
  if (tid < 16) {
    float bb = rbest[0][tid];
    int   bi = rbidx[0][tid];
#pragma unroll
    for (int q = 1; q < 4; ++q) {
      const float v = rbest[q][tid];
      if (v < bb) { bb = v; bi = rbidx[q][tid]; }   // strict <: lowest k wins
    }
    idxout[n0 + tid] = bi;
    out[IDX_OFF + n0 + tid] = (float)bi;            // fp32 index output
  }
}

// K2: gather codebook rows per block into LDS, write x_q_st (fp32), accumulate loss.
// Overwrites ALL of out's x_q region (including the cbT scratch area).
__global__ __launch_bounds__(256, 2)
void vq_gather_kernel(const float* __restrict__ x, const float* __restrict__ cb,
                      const int* __restrict__ idxin, float* __restrict__ loss_acc,
                      float* __restrict__ out) {
  __shared__ float qs[64][260];
  __shared__ int   idx_s[64];
  __shared__ float wr[4];

  const int tid  = threadIdx.x;
  const int lane = tid & 63;
  const int w    = tid >> 6;
  const int n0   = blockIdx.x << 6;
  const int b    = n0 >> 10;
  const int hw0  = n0 & 1023;

  if (tid < 64) idx_s[tid] = idxin[n0 + tid];
  __syncthreads();

  const float4* __restrict__ cb4 = (const float4*)cb;
  for (int r = w; r < 64; r += 4) {
    const int c = idx_s[r];
    const float4 v = cb4[((size_t)c << 6) + lane];  // coalesced 1KB row read per wave
    *(float4*)&qs[r][lane << 2] = v;
  }
  __syncthreads();

  float lsum = 0.f;
  const size_t obase = (size_t)b * (DD * HWC) + hw0 + lane;
  for (int i = 0; i < 64; ++i) {
    const int d = (w << 6) + i;
    const size_t o = obase + (size_t)d * HWC;
    const float q  = qs[lane][d];
    const float xv = x[o];
    {
#pragma clang fp contract(off)
      const float df = q - xv;           // fl(x_q - x)
      out[o] = xv + df;                  // x_q_st = fl(x + fl(x_q - x)), fp32
      lsum = fmaf(df, df, lsum);         // loss accumulation (loose threshold)
    }
  }

  for (int off = 32; off > 0; off >>= 1) lsum += __shfl_down(lsum, off, 64);
  if (lane == 0) wr[w] = lsum;
  __syncthreads();
  if (tid == 0) atomicAdd(loss_acc, (wr[0] + wr[1]) + (wr[2] + wr[3]));
}

// K3: loss = 1.5 * mean((x_q - x)^2), fp32
__global__ void vq_loss_kernel(const float* __restrict__ loss_acc,
                               float* __restrict__ out) {
  if (threadIdx.x == 0) {
    const float m = loss_acc[0] / 8388608.0f;
    out[LOSS_OFF] = m + 0.5f * m;
  }
}

extern "C" void kernel_launch(void* const* d_in, const int* in_sizes, int n_in,
                              void* d_out, int out_size, void* d_ws, size_t ws_size,
                              hipStream_t stream) {
  const float* x  = (const float*)d_in[0];   // [32,256,32,32] fp32
  const float* cb = (const float*)d_in[1];   // [1024,256] fp32
  float* out = (float*)d_out;                // [x_q_st | loss | indices] fp32

  float* esq      = (float*)d_ws;            // 1024 floats
  float* loss_acc = esq + 1024;              // 1 float (zeroed by K0 each call)
  int*   idxbuf   = (int*)(esq + 1040);      // 32768 ints
  float* cbT      = out + CBT_OFF;           // 256x1024 floats, overwritten by K2

  hipLaunchKernelGGL(vq_esq_kernel,       dim3(4),    dim3(256), 0, stream, cb, esq, loss_acc);
  hipLaunchKernelGGL(vq_transpose_kernel, dim3(256),  dim3(256), 0, stream, cb, cbT);
  hipLaunchKernelGGL(vq_argmin_kernel,    dim3(2048), dim3(256), 0, stream, x, cbT, esq, idxbuf, out);
  hipLaunchKernelGGL(vq_gather_kernel,    dim3(512),  dim3(256), 0, stream, x, cb, idxbuf, loss_acc, out);
  hipLaunchKernelGGL(vq_loss_kernel,      dim3(1),    dim3(64),  0, stream, loss_acc, out);
}